// Round 5
// baseline (580.936 us; speedup 1.0000x reference)
//
#include <hip/hip_runtime.h>

#define T_TOKENS 8192
#define IN_F 4096
#define OUT_F 11008

#define BM 256
#define BN 256
#define NT (IN_F / 64)   // 64 K-tiles of 64 (two k32-slices each)

typedef __attribute__((ext_vector_type(4))) int v4i;
typedef __attribute__((ext_vector_type(16))) int v16i;

// Fragment-major layout for both operands:
//   buf[blk][k32][lane][16B], lane = hi*32 + l31, holding
//   src[blk*32 + l31][k32*32 + hi*16 .. +16]   (16 int8)
// This is byte-identical to the mfma_i32_32x32x32_i8 A/B fragment each lane
// needs, so the GEMM loads operands directly global->VGPR, coalesced.

// ------------- Pass 1: fused quant (frag-major xq) + weight repack -------------
// Blocks [0,8192): one token row each. Blocks [8192,..): repack one (nblk,kg).
__global__ __launch_bounds__(256) void quant_repack_kernel(
        const float* __restrict__ x, signed char* __restrict__ xq,
        float* __restrict__ qscale, const int* __restrict__ w32,
        signed char* __restrict__ w8) {
    if (blockIdx.x < T_TOKENS) {
        const int row = blockIdx.x;
        const int t = threadIdx.x;
        // thread t owns floats [16t, 16t+16): contiguous 64B read
        const float4* xr = (const float4*)(x + (size_t)row * IN_F) + t * 4;
        float4 v[4];
        float am = 0.f;
#pragma unroll
        for (int i = 0; i < 4; ++i) {
            v[i] = xr[i];
            am = fmaxf(am, fmaxf(fmaxf(fabsf(v[i].x), fabsf(v[i].y)),
                                 fmaxf(fabsf(v[i].z), fabsf(v[i].w))));
        }
#pragma unroll
        for (int off = 32; off > 0; off >>= 1)
            am = fmaxf(am, __shfl_xor(am, off, 64));
        __shared__ float wmax[4];
        const int wv = t >> 6;
        if ((t & 63) == 0) wmax[wv] = am;
        __syncthreads();
        float amax = fmaxf(fmaxf(wmax[0], wmax[1]), fmaxf(wmax[2], wmax[3]));
        float qs = amax * (1.0f / 127.0f);
        if (qs < 1e-30f) qs = 1e-30f;
        const float inv = 1.0f / qs;
        if (t == 0) qscale[row] = qs;
        // quantize 16 values -> one 16B fragment store
        int q[16];
#pragma unroll
        for (int i = 0; i < 4; ++i) {
            q[i * 4 + 0] = max(-128, min(127, (int)rintf(v[i].x * inv)));
            q[i * 4 + 1] = max(-128, min(127, (int)rintf(v[i].y * inv)));
            q[i * 4 + 2] = max(-128, min(127, (int)rintf(v[i].z * inv)));
            q[i * 4 + 3] = max(-128, min(127, (int)rintf(v[i].w * inv)));
        }
        v4i p;
#pragma unroll
        for (int i = 0; i < 4; ++i)
            p[i] = (q[i * 4] & 255) | ((q[i * 4 + 1] & 255) << 8) |
                   ((q[i * 4 + 2] & 255) << 16) | ((q[i * 4 + 3] & 255) << 24);
        const int k32 = t >> 1, hi = t & 1;
        *(v4i*)(xq + (((size_t)(row >> 5)) * 128 + k32) * 1024 +
                ((hi * 32) + (row & 31)) * 16) = p;
    } else {
        // repack: block handles nblk (32 out-rows) x kg (128 k's = 4 k32)
        const int bb = blockIdx.x - T_TOKENS;
        const int nblk = bb >> 5;         // 0..343
        const int kg = bb & 31;           // 0..31
        const int t = threadIdx.x;
        __shared__ signed char tile[32][144];  // 128 + 16B pad
        // read: thread t -> row t>>3, 16 ints at k = kg*128 + (t&7)*16
        const int rrow = t >> 3, c8 = t & 7;
        const int* src = w32 + (size_t)(nblk * 32 + rrow) * IN_F + kg * 128 + c8 * 16;
        v4i pk;
#pragma unroll
        for (int j = 0; j < 4; ++j) {
            v4i w = ((const v4i*)src)[j];
            pk[j] = (w[0] & 255) | ((w[1] & 255) << 8) |
                    ((w[2] & 255) << 16) | ((w[3] & 255) << 24);
        }
        *(v4i*)&tile[rrow][c8 * 16] = pk;
        __syncthreads();
        // write: thread t -> k32l = t>>6, lane = t&63 -> coalesced 1KB stores
        const int k32l = t >> 6, lane = t & 63;
        const int hi = lane >> 5, l31 = lane & 31;
        v4i o = *(const v4i*)&tile[l31][k32l * 32 + hi * 16];
        *(v4i*)(w8 + ((size_t)(nblk)*128 + kg * 4 + k32l) * 1024 + lane * 16) = o;
    }
}

// ------------- Pass 2: LDS-free int8 GEMM (flatmm) -------------
// 8 waves (2M x 4N), per-wave 128x64 via acc[4][2] of mfma_i32_32x32x32_i8.
// Operands loaded directly global->VGPR from fragment-major xq/w8 (coalesced
// dwordx4, L1-resident working set). Register double-buffer, 1-tile prefetch.
// No LDS, no barriers; compiler emits counted vmcnt before first use.
__global__ __launch_bounds__(512, 2) void gemm_kernel(
        const signed char* __restrict__ A, const signed char* __restrict__ B,
        const float* __restrict__ qscale, const float* __restrict__ bias,
        const float* __restrict__ dqs, float* __restrict__ out) {
    const int tid = threadIdx.x;
    const int wid = tid >> 6;   // 0..7
    const int lane = tid & 63;
    const int wm = wid >> 2;    // 0..1
    const int wn = wid & 3;     // 0..3
    const int l31 = lane & 31;
    const int hi = lane >> 5;

    // XCD map: XCD k owns m-tiles [4k,4k+4), sweeps n. Bijective (1376 = 8*172).
    const int b = (int)blockIdx.x;
    const int xcd = b & 7;
    const int idx = b >> 3;
    const int m0 = (xcd * 4 + (idx & 3)) * BM;
    const int n0 = (idx >> 2) * BN;

    const signed char* Abase =
        A + ((size_t)((m0 >> 5) + wm * 4) * 128) * 1024 + lane * 16;
    const signed char* Bbase =
        B + ((size_t)((n0 >> 5) + wn * 2) * 128) * 1024 + lane * 16;

    v16i acc[4][2] = {};
    v4i A0[8], B0[4], A1[8], B1[4];

    // LOADSET(set, tau): load tile tau's fragments (k32 = 2tau, 2tau+1)
#define LOADSET(Aa, Bb, tau) do {                                              \
    _Pragma("unroll")                                                          \
    for (int im = 0; im < 4; ++im) {                                           \
        Aa[im * 2 + 0] = *(const v4i*)(Abase + ((size_t)(im * 128 + 2 * (tau))) * 1024);     \
        Aa[im * 2 + 1] = *(const v4i*)(Abase + ((size_t)(im * 128 + 2 * (tau) + 1)) * 1024); \
    }                                                                          \
    _Pragma("unroll")                                                          \
    for (int in = 0; in < 2; ++in) {                                           \
        Bb[in * 2 + 0] = *(const v4i*)(Bbase + ((size_t)(in * 128 + 2 * (tau))) * 1024);     \
        Bb[in * 2 + 1] = *(const v4i*)(Bbase + ((size_t)(in * 128 + 2 * (tau) + 1)) * 1024); \
    }                                                                          \
} while (0)

#define MFMASET(Aa, Bb) do {                                                   \
    __builtin_amdgcn_s_setprio(1);                                             \
    _Pragma("unroll")                                                          \
    for (int ks = 0; ks < 2; ++ks)                                             \
        _Pragma("unroll")                                                      \
        for (int im = 0; im < 4; ++im)                                         \
            _Pragma("unroll")                                                  \
            for (int in = 0; in < 2; ++in)                                     \
                acc[im][in] = __builtin_amdgcn_mfma_i32_32x32x32_i8(           \
                    Aa[im * 2 + ks], Bb[in * 2 + ks], acc[im][in], 0, 0, 0);   \
    __builtin_amdgcn_s_setprio(0);                                             \
} while (0)

    LOADSET(A0, B0, 0);
    LOADSET(A1, B1, 1);
    for (int tau = 0; tau < NT; tau += 2) {
        MFMASET(A0, B0);
        if (tau + 2 < NT) LOADSET(A0, B0, tau + 2);
        MFMASET(A1, B1);
        if (tau + 3 < NT) LOADSET(A1, B1, tau + 3);
    }
#undef LOADSET
#undef MFMASET

    // ---- epilogue: dequant + bias ----
    const float dq = dqs[0];
#pragma unroll
    for (int im = 0; im < 4; ++im) {
        float qsv[16];
#pragma unroll
        for (int r = 0; r < 16; ++r) {
            const int trow = wm * 128 + im * 32 + (r & 3) + 8 * (r >> 2) + 4 * hi;
            qsv[r] = dq * qscale[m0 + trow];
        }
#pragma unroll
        for (int in = 0; in < 2; ++in) {
            const int col = n0 + wn * 64 + in * 32 + l31;
            const float bv = bias[col];
#pragma unroll
            for (int r = 0; r < 16; ++r) {
                const int trow = wm * 128 + im * 32 + (r & 3) + 8 * (r >> 2) + 4 * hi;
                out[(size_t)(m0 + trow) * OUT_F + col] =
                    qsv[r] * (float)acc[im][in][r] + bv;
            }
        }
    }
}

extern "C" void kernel_launch(void* const* d_in, const int* in_sizes, int n_in,
                              void* d_out, int out_size, void* d_ws, size_t ws_size,
                              hipStream_t stream) {
    const float* x    = (const float*)d_in[0];
    const int*   w32  = (const int*)d_in[1];   // int8 values stored as int32
    const float* bias = (const float*)d_in[2];
    const float* dqs  = (const float*)d_in[3];
    float* out = (float*)d_out;

    signed char* xq = (signed char*)d_ws;                                   // 33.55 MB
    float* qscale   = (float*)((char*)d_ws + (size_t)T_TOKENS * IN_F);      // 32 KB
    signed char* w8 = (signed char*)((char*)d_ws + (size_t)T_TOKENS * IN_F
                                     + (size_t)T_TOKENS * 4);               // 45.1 MB

    // 8192 quant blocks + 344*32 = 11008 repack blocks
    quant_repack_kernel<<<T_TOKENS + (OUT_F / 32) * 32, 256, 0, stream>>>(
        x, xq, qscale, w32, w8);
    dim3 g((T_TOKENS / BM) * (OUT_F / BN));  // 1376
    gemm_kernel<<<g, 512, 0, stream>>>(xq, w8, qscale, bias, dqs, out);
}

// Round 6
// 556.703 us; speedup vs baseline: 1.0435x; 1.0435x over previous
//
#include <hip/hip_runtime.h>

#define T_TOKENS 8192
#define IN_F 4096
#define OUT_F 11008

#define BM 256
#define BN 256
#define NT (IN_F / 64)   // 64 K-tiles of 64 (two k32-slices each)

typedef __attribute__((ext_vector_type(4))) int v4i;
typedef __attribute__((ext_vector_type(16))) int v16i;

__device__ __forceinline__ void load_lds16(const signed char* g, const signed char* l) {
    __builtin_amdgcn_global_load_lds(
        (const __attribute__((address_space(1))) void*)g,
        (__attribute__((address_space(3))) void*)l, 16, 0, 0);
}

// Fragment-major layout for both operands:
//   buf[blk32][k32][lane][16B], lane = hi*32 + l31, holding
//   src[blk*32 + l31][k32*32 + hi*16 .. +16]   (16 int8)
// Byte-identical to the mfma_i32_32x32x32_i8 A/B fragment per lane -> GEMM
// consumes it with contiguous (conflict-free) LDS reads / coalesced global reads.

// ------------- Pass 1: fused quant (frag-major xq) + weight repack -------------
__global__ __launch_bounds__(256) void quant_repack_kernel(
        const float* __restrict__ x, signed char* __restrict__ xq,
        float* __restrict__ qscale, const int* __restrict__ w32,
        signed char* __restrict__ w8) {
    if (blockIdx.x < T_TOKENS) {
        const int row = blockIdx.x;
        const int t = threadIdx.x;
        const float4* xr = (const float4*)(x + (size_t)row * IN_F) + t * 4;
        float4 v[4];
        float am = 0.f;
#pragma unroll
        for (int i = 0; i < 4; ++i) {
            v[i] = xr[i];
            am = fmaxf(am, fmaxf(fmaxf(fabsf(v[i].x), fabsf(v[i].y)),
                                 fmaxf(fabsf(v[i].z), fabsf(v[i].w))));
        }
#pragma unroll
        for (int off = 32; off > 0; off >>= 1)
            am = fmaxf(am, __shfl_xor(am, off, 64));
        __shared__ float wmax[4];
        const int wv = t >> 6;
        if ((t & 63) == 0) wmax[wv] = am;
        __syncthreads();
        float amax = fmaxf(fmaxf(wmax[0], wmax[1]), fmaxf(wmax[2], wmax[3]));
        float qs = amax * (1.0f / 127.0f);
        if (qs < 1e-30f) qs = 1e-30f;
        const float inv = 1.0f / qs;
        if (t == 0) qscale[row] = qs;
        int q[16];
#pragma unroll
        for (int i = 0; i < 4; ++i) {
            q[i * 4 + 0] = max(-128, min(127, (int)rintf(v[i].x * inv)));
            q[i * 4 + 1] = max(-128, min(127, (int)rintf(v[i].y * inv)));
            q[i * 4 + 2] = max(-128, min(127, (int)rintf(v[i].z * inv)));
            q[i * 4 + 3] = max(-128, min(127, (int)rintf(v[i].w * inv)));
        }
        v4i p;
#pragma unroll
        for (int i = 0; i < 4; ++i)
            p[i] = (q[i * 4] & 255) | ((q[i * 4 + 1] & 255) << 8) |
                   ((q[i * 4 + 2] & 255) << 16) | ((q[i * 4 + 3] & 255) << 24);
        const int k32 = t >> 1, hi = t & 1;
        *(v4i*)(xq + (((size_t)(row >> 5)) * 128 + k32) * 1024 +
                ((hi * 32) + (row & 31)) * 16) = p;
    } else {
        const int bb = blockIdx.x - T_TOKENS;
        const int nblk = bb >> 5;
        const int kg = bb & 31;
        const int t = threadIdx.x;
        __shared__ signed char tile[32][144];
        const int rrow = t >> 3, c8 = t & 7;
        const int* src = w32 + (size_t)(nblk * 32 + rrow) * IN_F + kg * 128 + c8 * 16;
        v4i pk;
#pragma unroll
        for (int j = 0; j < 4; ++j) {
            v4i w = ((const v4i*)src)[j];
            pk[j] = (w[0] & 255) | ((w[1] & 255) << 8) |
                    ((w[2] & 255) << 16) | ((w[3] & 255) << 24);
        }
        *(v4i*)&tile[rrow][c8 * 16] = pk;
        __syncthreads();
        const int k32l = t >> 6, lane = t & 63;
        const int hi = lane >> 5, l31 = lane & 31;
        v4i o = *(const v4i*)&tile[l31][k32l * 32 + hi * 16];
        *(v4i*)(w8 + ((size_t)(nblk)*128 + kg * 4 + k32l) * 1024 + lane * 16) = o;
    }
}

// ------------- Pass 2: hybrid int8 GEMM -------------
// 8 waves (2M x 4N), per-wave 128x64 via acc[4][2] of mfma_i32_32x32x32_i8.
// A (4x wave-dup) staged in LDS frag-major: 4 bufs x 16KB, depth-3 gload_lds.
// B (2x wave-dup) direct global->VGPR, 4 register sets, depth-2.
// One barrier + one counted vmcnt per K-tile; issue order per sub-iter is
// [A-stage(t+3) x2, B-load(t+2) x4] -> exact counts 12/16/8.
__global__ __launch_bounds__(512, 2) void gemm_kernel(
        const signed char* __restrict__ A, const signed char* __restrict__ B,
        const float* __restrict__ qscale, const float* __restrict__ bias,
        const float* __restrict__ dqs, float* __restrict__ out) {
    __shared__ __align__(16) signed char smem[4 * 16384];  // 64 KB

    const int tid = threadIdx.x;
    const int wid = tid >> 6;   // 0..7
    const int lane = tid & 63;
    const int wm = wid >> 2;    // 0..1
    const int wn = wid & 3;     // 0..3
    const int l31 = lane & 31;
    const int hi = lane >> 5;

    // XCD map: XCD k owns m-tiles [4k,4k+4), sweeps n. Bijective (1376 = 8*172).
    const int b = (int)blockIdx.x;
    const int xcd = b & 7;
    const int idx = b >> 3;
    const int m0 = (xcd * 4 + (idx & 3)) * BM;
    const int n0 = (idx >> 2) * BN;

    // A staging: 16 KB tile = 8 mblk x 2 k32 x 1KB; thread -> linear LDS
    // (c*8192 + wid*1024 + lane*16); matching global frag-major source.
    const signed char* aSrc[2];
    int ldsA[2];
#pragma unroll
    for (int c = 0; c < 2; ++c) {
        const int mloc = c * 4 + (wid >> 1);
        const int inner = (wid & 1) * 1024 + lane * 16;
        aSrc[c] = A + ((size_t)((m0 >> 5) + mloc)) * 131072 + inner;
        ldsA[c] = c * 8192 + wid * 1024;
    }
    const signed char* bSrc[2];
#pragma unroll
    for (int in = 0; in < 2; ++in)
        bSrc[in] = B + ((size_t)((n0 >> 5) + wn * 2 + in)) * 131072 + lane * 16;

    v16i acc[4][2] = {};
    v4i Bf0[4], Bf1[4], Bf2[4], Bf3[4];

    // ---- prologue: A(0,1,2) -> bufs 0,1,2 ; B(0)->Bf0, B(1)->Bf1 ----
#pragma unroll
    for (int tt = 0; tt < 3; ++tt) {
        load_lds16(aSrc[0] + tt * 2048, smem + tt * 16384 + ldsA[0]);
        load_lds16(aSrc[1] + tt * 2048, smem + tt * 16384 + ldsA[1]);
    }
    __builtin_amdgcn_sched_barrier(0);
#pragma unroll
    for (int in = 0; in < 2; ++in)
#pragma unroll
        for (int ks = 0; ks < 2; ++ks) {
            Bf0[in * 2 + ks] = *(const v4i*)(bSrc[in] + ks * 1024);
            Bf1[in * 2 + ks] = *(const v4i*)(bSrc[in] + 2048 + ks * 1024);
        }

#define SUB(tau, j, Bcur, Bld) do {                                            \
    if ((tau) == 0)                                                            \
        asm volatile("s_waitcnt vmcnt(12)" ::: "memory");                      \
    else if ((tau) + 3 < NT)                                                   \
        asm volatile("s_waitcnt vmcnt(16)" ::: "memory");                      \
    else                                                                       \
        asm volatile("s_waitcnt vmcnt(8)" ::: "memory");                       \
    __builtin_amdgcn_sched_barrier(0);                                         \
    __builtin_amdgcn_s_barrier();                                              \
    __builtin_amdgcn_sched_barrier(0);                                         \
    if ((tau) + 3 < NT) {                                                      \
        load_lds16(aSrc[0] + ((tau) + 3) * 2048,                               \
                   smem + (((j) + 3) & 3) * 16384 + ldsA[0]);                  \
        load_lds16(aSrc[1] + ((tau) + 3) * 2048,                               \
                   smem + (((j) + 3) & 3) * 16384 + ldsA[1]);                  \
    }                                                                          \
    __builtin_amdgcn_sched_barrier(0);                                         \
    if ((tau) + 2 < NT) {                                                      \
        _Pragma("unroll")                                                      \
        for (int in = 0; in < 2; ++in)                                         \
            _Pragma("unroll")                                                  \
            for (int ks = 0; ks < 2; ++ks)                                     \
                Bld[in * 2 + ks] = *(const v4i*)(bSrc[in] +                    \
                    ((size_t)((tau) + 2)) * 2048 + ks * 1024);                 \
    }                                                                          \
    v4i afr[4][2];                                                             \
    _Pragma("unroll")                                                          \
    for (int im = 0; im < 4; ++im)                                             \
        _Pragma("unroll")                                                      \
        for (int ks = 0; ks < 2; ++ks)                                         \
            afr[im][ks] = *(const v4i*)(smem + (j) * 16384 +                   \
                (wm * 4 + im) * 2048 + ks * 1024 + lane * 16);                 \
    __builtin_amdgcn_s_setprio(1);                                             \
    _Pragma("unroll")                                                          \
    for (int ks = 0; ks < 2; ++ks)                                             \
        _Pragma("unroll")                                                      \
        for (int im = 0; im < 4; ++im)                                         \
            _Pragma("unroll")                                                  \
            for (int in = 0; in < 2; ++in)                                     \
                acc[im][in] = __builtin_amdgcn_mfma_i32_32x32x32_i8(           \
                    afr[im][ks], Bcur[in * 2 + ks], acc[im][in], 0, 0, 0);     \
    __builtin_amdgcn_s_setprio(0);                                             \
} while (0)

    for (int tt = 0; tt < NT; tt += 4) {
        SUB(tt + 0, 0, Bf0, Bf2);
        SUB(tt + 1, 1, Bf1, Bf3);
        SUB(tt + 2, 2, Bf2, Bf0);
        SUB(tt + 3, 3, Bf3, Bf1);
    }
#undef SUB

    // ---- epilogue: dequant + bias ----
    const float dq = dqs[0];
#pragma unroll
    for (int im = 0; im < 4; ++im) {
        float qsv[16];
#pragma unroll
        for (int r = 0; r < 16; ++r) {
            const int trow = wm * 128 + im * 32 + (r & 3) + 8 * (r >> 2) + 4 * hi;
            qsv[r] = dq * qscale[m0 + trow];
        }
#pragma unroll
        for (int in = 0; in < 2; ++in) {
            const int col = n0 + wn * 64 + in * 32 + l31;
            const float bv = bias[col];
#pragma unroll
            for (int r = 0; r < 16; ++r) {
                const int trow = wm * 128 + im * 32 + (r & 3) + 8 * (r >> 2) + 4 * hi;
                out[(size_t)(m0 + trow) * OUT_F + col] =
                    qsv[r] * (float)acc[im][in][r] + bv;
            }
        }
    }
}

extern "C" void kernel_launch(void* const* d_in, const int* in_sizes, int n_in,
                              void* d_out, int out_size, void* d_ws, size_t ws_size,
                              hipStream_t stream) {
    const float* x    = (const float*)d_in[0];
    const int*   w32  = (const int*)d_in[1];   // int8 values stored as int32
    const float* bias = (const float*)d_in[2];
    const float* dqs  = (const float*)d_in[3];
    float* out = (float*)d_out;

    signed char* xq = (signed char*)d_ws;                                   // 33.55 MB
    float* qscale   = (float*)((char*)d_ws + (size_t)T_TOKENS * IN_F);      // 32 KB
    signed char* w8 = (signed char*)((char*)d_ws + (size_t)T_TOKENS * IN_F
                                     + (size_t)T_TOKENS * 4);               // 45.1 MB

    quant_repack_kernel<<<T_TOKENS + (OUT_F / 32) * 32, 256, 0, stream>>>(
        x, xq, qscale, w32, w8);
    dim3 g((T_TOKENS / BM) * (OUT_F / BN));  // 1376
    gemm_kernel<<<g, 512, 0, stream>>>(xq, w8, qscale, bias, dqs, out);
}

// Round 7
// 457.216 us; speedup vs baseline: 1.2706x; 1.2176x over previous
//
#include <hip/hip_runtime.h>

#define T_TOKENS 8192
#define IN_F 4096
#define OUT_F 11008

#define BM 256
#define BN 256
#define NT (IN_F / 64)   // 64 K-tiles of 64 (two k32-slices each)

typedef __attribute__((ext_vector_type(4))) int v4i;
typedef __attribute__((ext_vector_type(16))) int v16i;

__device__ __forceinline__ void load_lds16(const signed char* g, const signed char* l) {
    __builtin_amdgcn_global_load_lds(
        (const __attribute__((address_space(1))) void*)g,
        (__attribute__((address_space(3))) void*)l, 16, 0, 0);
}

// Fragment-major layout for both operands:
//   buf[blk32][k32][lane][16B], lane = hi*32 + l31, holding
//   src[blk*32 + l31][k32*32 + hi*16 .. +16]   (16 int8)
// Byte-identical to the mfma_i32_32x32x32_i8 A/B fragment per lane.

// ------------- Pass 1: fused quant (frag-major xq) + weight repack -------------
__global__ __launch_bounds__(256) void quant_repack_kernel(
        const float* __restrict__ x, signed char* __restrict__ xq,
        float* __restrict__ qscale, const int* __restrict__ w32,
        signed char* __restrict__ w8) {
    if (blockIdx.x < T_TOKENS) {
        const int row = blockIdx.x;
        const int t = threadIdx.x;
        const float4* xr = (const float4*)(x + (size_t)row * IN_F) + t * 4;
        float4 v[4];
        float am = 0.f;
#pragma unroll
        for (int i = 0; i < 4; ++i) {
            v[i] = xr[i];
            am = fmaxf(am, fmaxf(fmaxf(fabsf(v[i].x), fabsf(v[i].y)),
                                 fmaxf(fabsf(v[i].z), fabsf(v[i].w))));
        }
#pragma unroll
        for (int off = 32; off > 0; off >>= 1)
            am = fmaxf(am, __shfl_xor(am, off, 64));
        __shared__ float wmax[4];
        const int wv = t >> 6;
        if ((t & 63) == 0) wmax[wv] = am;
        __syncthreads();
        float amax = fmaxf(fmaxf(wmax[0], wmax[1]), fmaxf(wmax[2], wmax[3]));
        float qs = amax * (1.0f / 127.0f);
        if (qs < 1e-30f) qs = 1e-30f;
        const float inv = 1.0f / qs;
        if (t == 0) qscale[row] = qs;
        int q[16];
#pragma unroll
        for (int i = 0; i < 4; ++i) {
            q[i * 4 + 0] = max(-128, min(127, (int)rintf(v[i].x * inv)));
            q[i * 4 + 1] = max(-128, min(127, (int)rintf(v[i].y * inv)));
            q[i * 4 + 2] = max(-128, min(127, (int)rintf(v[i].z * inv)));
            q[i * 4 + 3] = max(-128, min(127, (int)rintf(v[i].w * inv)));
        }
        v4i p;
#pragma unroll
        for (int i = 0; i < 4; ++i)
            p[i] = (q[i * 4] & 255) | ((q[i * 4 + 1] & 255) << 8) |
                   ((q[i * 4 + 2] & 255) << 16) | ((q[i * 4 + 3] & 255) << 24);
        const int k32 = t >> 1, hi = t & 1;
        *(v4i*)(xq + (((size_t)(row >> 5)) * 128 + k32) * 1024 +
                ((hi * 32) + (row & 31)) * 16) = p;
    } else {
        const int bb = blockIdx.x - T_TOKENS;
        const int nblk = bb >> 5;
        const int kg = bb & 31;
        const int t = threadIdx.x;
        __shared__ signed char tile[32][144];
        const int rrow = t >> 3, c8 = t & 7;
        const int* src = w32 + (size_t)(nblk * 32 + rrow) * IN_F + kg * 128 + c8 * 16;
        v4i pk;
#pragma unroll
        for (int j = 0; j < 4; ++j) {
            v4i w = ((const v4i*)src)[j];
            pk[j] = (w[0] & 255) | ((w[1] & 255) << 8) |
                    ((w[2] & 255) << 16) | ((w[3] & 255) << 24);
        }
        *(v4i*)&tile[rrow][c8 * 16] = pk;
        __syncthreads();
        const int k32l = t >> 6, lane = t & 63;
        const int hi = lane >> 5, l31 = lane & 31;
        v4i o = *(const v4i*)&tile[l31][k32l * 32 + hi * 16];
        *(v4i*)(w8 + ((size_t)(nblk)*128 + kg * 4 + k32l) * 1024 + lane * 16) = o;
    }
}

// ------------- Pass 2: int8 GEMM, 4 waves x (128x128), frag-major LDS -------
// Block 256x256, 4 waves (2x2), per-wave 128x128 via acc[4][4] (256 AGPR).
// LDS: ring of 4 x 32KB bufs (A 16KB | B 16KB), frag-major -> contiguous
// conflict-free ds_read_b128 and linear gload_lds staging (no swizzle).
// Per K-tile: stage t+3 (8 gload/wave) -> vmcnt(16) -> lgkmcnt(0) -> barrier
// -> ds_read frags(t+1) interleaved (compiler-scheduled) with 32 MFMA of t.
// 1 wave/SIMD: all hiding is ILP; lgkmcnt(0)-before-barrier closes the
// ring-4 stage-overwrite race.
__global__ __launch_bounds__(256, 1) void gemm_kernel(
        const signed char* __restrict__ A, const signed char* __restrict__ B,
        const float* __restrict__ qscale, const float* __restrict__ bias,
        const float* __restrict__ dqs, float* __restrict__ out) {
    __shared__ __align__(16) signed char smem_[4 * 32768];  // 128 KB
    signed char* smem = smem_;

    const int tid = threadIdx.x;
    const int wid = tid >> 6;   // 0..3
    const int lane = tid & 63;
    const int wm = wid >> 1;    // 0..1
    const int wn = wid & 1;     // 0..1
    const int l31 = lane & 31;
    const int hi = lane >> 5;

    // XCD map: XCD k owns m-tiles [4k,4k+4), sweeps n. Bijective (1376 = 8*172).
    const int b = (int)blockIdx.x;
    const int xcd = b & 7;
    const int idx = b >> 3;
    const int m0 = (xcd * 4 + (idx & 3)) * BM;
    const int n0 = (idx >> 2) * BN;

    // staging: wave w stages mblk/nblk {2w, 2w+1}, 8 gload_lds (1KB each)/tile
    const signed char* aS[2];
    const signed char* bS[2];
    int ldS[2];
#pragma unroll
    for (int j = 0; j < 2; ++j) {
        aS[j] = A + ((size_t)((m0 >> 5) + 2 * wid + j)) * 131072 + lane * 16;
        bS[j] = B + ((size_t)((n0 >> 5) + 2 * wid + j)) * 131072 + lane * 16;
        ldS[j] = (2 * wid + j) * 2048;  // wave-uniform; HW adds lane*16
    }
    // fragment read offsets (contiguous per wave -> conflict-free)
    int rdA[4], rdB[4];
#pragma unroll
    for (int im = 0; im < 4; ++im) rdA[im] = (wm * 4 + im) * 2048 + lane * 16;
#pragma unroll
    for (int in = 0; in < 4; ++in) rdB[in] = 16384 + (wn * 4 + in) * 2048 + lane * 16;

    v16i acc[4][4] = {};
    v4i a0[4][2], b0[4][2], a1[4][2], b1[4][2];

    // ---- prologue: stage tiles 0,1,2 into bufs 0,1,2 ----
#pragma unroll
    for (int tt = 0; tt < 3; ++tt)
#pragma unroll
        for (int j = 0; j < 2; ++j)
#pragma unroll
            for (int ks = 0; ks < 2; ++ks) {
                load_lds16(aS[j] + tt * 2048 + ks * 1024,
                           smem + tt * 32768 + ldS[j] + ks * 1024);
                load_lds16(bS[j] + tt * 2048 + ks * 1024,
                           smem + tt * 32768 + 16384 + ldS[j] + ks * 1024);
            }
    asm volatile("s_waitcnt vmcnt(16)" ::: "memory");  // tile 0 landed
    __builtin_amdgcn_sched_barrier(0);
    __builtin_amdgcn_s_barrier();
    __builtin_amdgcn_sched_barrier(0);
    // read frags(0) into set0
#pragma unroll
    for (int im = 0; im < 4; ++im)
#pragma unroll
        for (int ks = 0; ks < 2; ++ks)
            a0[im][ks] = *(const v4i*)(smem + rdA[im] + ks * 1024);
#pragma unroll
    for (int in = 0; in < 4; ++in)
#pragma unroll
        for (int ks = 0; ks < 2; ++ks)
            b0[in][ks] = *(const v4i*)(smem + rdB[in] + ks * 1024);

#define PHASE(p, CA, CB, NA, NB, DOSTAGE, VMC, DOREAD) do {                    \
    if (DOSTAGE) {                                                             \
        const int bn_ = ((p) + 3) & 3;                                         \
        const int ko_ = ((p) + 3) * 2048;                                      \
        _Pragma("unroll")                                                      \
        for (int j = 0; j < 2; ++j)                                            \
            _Pragma("unroll")                                                  \
            for (int ks = 0; ks < 2; ++ks) {                                   \
                load_lds16(aS[j] + ko_ + ks * 1024,                            \
                           smem + bn_ * 32768 + ldS[j] + ks * 1024);           \
                load_lds16(bS[j] + ko_ + ks * 1024,                            \
                           smem + bn_ * 32768 + 16384 + ldS[j] + ks * 1024);   \
            }                                                                  \
    }                                                                          \
    asm volatile("s_waitcnt vmcnt(" #VMC ")" ::: "memory");                    \
    asm volatile("s_waitcnt lgkmcnt(0)" ::: "memory");                         \
    __builtin_amdgcn_sched_barrier(0);                                         \
    __builtin_amdgcn_s_barrier();                                              \
    __builtin_amdgcn_sched_barrier(0);                                         \
    if (DOREAD) {                                                              \
        const signed char* rb_ = smem + (((p) + 1) & 3) * 32768;               \
        _Pragma("unroll")                                                      \
        for (int im = 0; im < 4; ++im)                                         \
            _Pragma("unroll")                                                  \
            for (int ks = 0; ks < 2; ++ks)                                     \
                NA[im][ks] = *(const v4i*)(rb_ + rdA[im] + ks * 1024);         \
        _Pragma("unroll")                                                      \
        for (int in = 0; in < 4; ++in)                                         \
            _Pragma("unroll")                                                  \
            for (int ks = 0; ks < 2; ++ks)                                     \
                NB[in][ks] = *(const v4i*)(rb_ + rdB[in] + ks * 1024);         \
    }                                                                          \
    _Pragma("unroll")                                                          \
    for (int ks = 0; ks < 2; ++ks)                                             \
        _Pragma("unroll")                                                      \
        for (int im = 0; im < 4; ++im)                                         \
            _Pragma("unroll")                                                  \
            for (int in = 0; in < 4; ++in)                                     \
                acc[im][in] = __builtin_amdgcn_mfma_i32_32x32x32_i8(           \
                    CA[im][ks], CB[in][ks], acc[im][in], 0, 0, 0);             \
} while (0)

    for (int i = 0; i < NT - 4; i += 2) {
        PHASE(i,     a0, b0, a1, b1, true, 16, true);
        PHASE(i + 1, a1, b1, a0, b0, true, 16, true);
    }
    PHASE(NT - 4, a0, b0, a1, b1, true,  16, true);   // p=60: stages tile 63
    PHASE(NT - 3, a1, b1, a0, b0, false, 8,  true);
    PHASE(NT - 2, a0, b0, a1, b1, false, 0,  true);
    PHASE(NT - 1, a1, b1, a0, b0, false, 0,  false);
#undef PHASE

    // ---- epilogue: dequant + bias ----
    const float dq = dqs[0];
#pragma unroll
    for (int im = 0; im < 4; ++im) {
        float qsv[16];
#pragma unroll
        for (int r = 0; r < 16; ++r) {
            const int trow = wm * 128 + im * 32 + (r & 3) + 8 * (r >> 2) + 4 * hi;
            qsv[r] = dq * qscale[m0 + trow];
        }
#pragma unroll
        for (int in = 0; in < 4; ++in) {
            const int col = n0 + wn * 128 + in * 32 + l31;
            const float bv = bias[col];
#pragma unroll
            for (int r = 0; r < 16; ++r) {
                const int trow = wm * 128 + im * 32 + (r & 3) + 8 * (r >> 2) + 4 * hi;
                out[(size_t)(m0 + trow) * OUT_F + col] =
                    qsv[r] * (float)acc[im][in][r] + bv;
            }
        }
    }
}

extern "C" void kernel_launch(void* const* d_in, const int* in_sizes, int n_in,
                              void* d_out, int out_size, void* d_ws, size_t ws_size,
                              hipStream_t stream) {
    const float* x    = (const float*)d_in[0];
    const int*   w32  = (const int*)d_in[1];   // int8 values stored as int32
    const float* bias = (const float*)d_in[2];
    const float* dqs  = (const float*)d_in[3];
    float* out = (float*)d_out;

    signed char* xq = (signed char*)d_ws;                                   // 33.55 MB
    float* qscale   = (float*)((char*)d_ws + (size_t)T_TOKENS * IN_F);      // 32 KB
    signed char* w8 = (signed char*)((char*)d_ws + (size_t)T_TOKENS * IN_F
                                     + (size_t)T_TOKENS * 4);               // 45.1 MB

    quant_repack_kernel<<<T_TOKENS + (OUT_F / 32) * 32, 256, 0, stream>>>(
        x, xq, qscale, w32, w8);
    dim3 g((T_TOKENS / BM) * (OUT_F / BN));  // 1376
    gemm_kernel<<<g, 256, 0, stream>>>(xq, w8, qscale, bias, dqs, out);
}